// Round 9
// baseline (145.360 us; speedup 1.0000x reference)
//
#include <hip/hip_runtime.h>
#include <math.h>

// Problem constants
#define BB 16
#define HH 128
#define WW 128
#define RR 4      // reward_dim
#define AA 8      // action_channels
#define II 5      // R+1
#define CC 45     // I*K*K
#define NPIX (BB*HH*WW)
#define LOG2E 1.4426950408889634f
#define RS 72     // LDS row stride (144 B): 16B-aligned frags, 2-way-free banks

typedef __attribute__((ext_vector_type(8))) short v8s;      // 8 x bf16 (MFMA A/B frag)
typedef __attribute__((ext_vector_type(4))) float v4f;      // MFMA C/D frag
typedef __attribute__((ext_vector_type(4))) unsigned short v4u16;

// Repacked bf16 weight fragments, ELEMENT index:
//   e = (o*6 + mt*2 + ks)*512 + lane*8 + j
// Lane l holds A[ch = mt*16 + (l&15)][k = ks*32 + (l>>4)*8 + j], pre-scaled by
// log2(e).  M pad 45->48 (zero rows), K pad 45->64 (zeros).
__device__ __align__(16) unsigned short g_wbf[AA * 3072];   // 24576 elements
__device__ float g_sink[NPIX];   // ablation-variant sink (never validated)

__device__ __forceinline__ unsigned short f2bf(float f) {
    union { float f; unsigned int u; } v; v.f = f;
    unsigned int r = v.u + 0x7fffu + ((v.u >> 16) & 1u);   // round-to-nearest-even
    return (unsigned short)(r >> 16);
}

__global__ __launch_bounds__(256) void repack_kernel(const float* __restrict__ w) {
    const int e = blockIdx.x * 256 + threadIdx.x;
    if (e >= AA * 3072) return;
    const int o    = e / 3072;
    const int rem  = e - o * 3072;
    const int mtks = rem >> 9;            // 0..5
    const int l    = (rem >> 3) & 63;     // lane
    const int j    = rem & 7;
    const int mt   = mtks >> 1;
    const int ks   = mtks & 1;
    const int ch   = mt * 16 + (l & 15);          // 0..47
    const int k    = ks * 32 + (l >> 4) * 8 + j;  // 0..63
    float v = 0.0f;
    if (ch < CC && k < CC) v = w[(o * CC + ch) * CC + k] * LOG2E;
    g_wbf[e] = f2bf(v);
}

// ---- fused kernel, template-ablated (rule #17: asm keep-alives, no DCE) ----
// V=0 FULL (writes d_out) -- identical to the round-5-benched best (~39us).
// V=1 STAGE   : staging + Bf/pu loads + 8 token MFMAs, no o-loop.
// V=4 MFMAONLY: staging + full o-loop MFMAs, softmax replaced by asm keeps.
// V=2 NOEXP   : FULL with e = acc (exp2 removed), everything else identical.
template<int V>
__global__ __launch_bounds__(128, 4) void vi_var(
    const float* __restrict__ values,   // [B,H,W]
    const float* __restrict__ rewards,  // [B,R,H,W]
    float* __restrict__ outp)           // d_out (V==0) -- others use g_sink
{
    __shared__ __align__(16) unsigned short lds[2 * 64 * RS]; // 18432 B
    const int lane = threadIdx.x & 63;
    const int wv   = threadIdx.x >> 6;
    const int c    = lane & 15;        // pixel within tile / D col
    const int g    = lane >> 4;        // lane group
    const int row  = blockIdx.x;       // b*128 + h
    const int b    = row >> 7;
    const int h    = row & 127;
    const int w0   = wv * 64;
    const int P0   = row * 128 + w0;
    const int wbase = wv * (64 * RS);

    // zero-fill this wave's region (covers K pad 45..71)
    {
        v8s z = {0,0,0,0,0,0,0,0};
        #pragma unroll
        for (int qq = 0; qq < 9; ++qq)
            *(v8s*)(&lds[wbase + lane * RS + qq * 8]) = z;
    }

    // stage patches: lane (c,g) writes pixel c of each tile, elems j = g*12+tt
    #pragma unroll
    for (int t = 0; t < 4; ++t) {
        const int pw = w0 + t * 16 + c;
        #pragma unroll
        for (int tt = 0; tt < 12; ++tt) {
            const int j = g * 12 + tt;
            if (j < CC) {
                const int i  = j / 9;
                const int r9 = j - i * 9;
                const int k1 = r9 / 3;
                const int k2 = r9 - k1 * 3;
                const int y = h + k1 - 1;
                const int x = pw + k2 - 1;
                float f = 0.0f;
                if (y >= 0 && y < HH && x >= 0 && x < WW)
                    f = (i < RR) ? rewards[((b * RR + i) * HH + y) * WW + x]
                                 : values[(b * HH + y) * WW + x];
                lds[wbase + (t * 16 + c) * RS + j] = f2bf(f);
            }
        }
    }

    // B fragments: lane (c,g) holds patch[pix=c][k = ks*32 + g*8 + 0..7]
    v8s Bf[4][2];
    #pragma unroll
    for (int t = 0; t < 4; ++t)
        #pragma unroll
        for (int ks = 0; ks < 2; ++ks)
            Bf[t][ks] = *(const v8s*)(&lds[wbase + (t * 16 + c) * RS + ks * 32 + g * 8]);

    // patch weights for q (o-invariant), kept packed (12 VGPR)
    v4u16 pu[4][3];
    #pragma unroll
    for (int t = 0; t < 4; ++t)
        #pragma unroll
        for (int mt = 0; mt < 3; ++mt)
            pu[t][mt] = *(const v4u16*)(&lds[wbase + (t * 16 + c) * RS
                                             + mt * 16 + g * 4]);

    if constexpr (V == 1) {
        // STAGE: consume Bf fully via 8 token MFMAs, pu via cheap adds
        float sink = 0.f;
        #pragma unroll
        for (int t = 0; t < 4; ++t) {
            v4f a0 = (v4f){0.f, 0.f, 0.f, 0.f};
            a0 = __builtin_amdgcn_mfma_f32_16x16x32_bf16(Bf[t][0], Bf[t][0], a0, 0, 0, 0);
            a0 = __builtin_amdgcn_mfma_f32_16x16x32_bf16(Bf[t][1], Bf[t][1], a0, 0, 0, 0);
            sink += a0[0] + a0[1] + a0[2] + a0[3];
            #pragma unroll
            for (int mt = 0; mt < 3; ++mt)
                sink += (float)(pu[t][mt][0] + pu[t][mt][3]);
        }
        if (g == 0) g_sink[P0 + c] = sink;
        return;
    } else {
        float best[4] = {-1e30f, -1e30f, -1e30f, -1e30f};
        const unsigned short* wb = g_wbf;

        #pragma unroll 1
        for (int o = 0; o < AA; ++o) {
            v8s Af[3][2];
            #pragma unroll
            for (int mt = 0; mt < 3; ++mt)
                #pragma unroll
                for (int ks = 0; ks < 2; ++ks)
                    Af[mt][ks] = *(const v8s*)(wb + (o * 6 + mt * 2 + ks) * 512 + lane * 8);
            #pragma unroll
            for (int t = 0; t < 4; ++t) {
                v4f acc[3];
                #pragma unroll
                for (int mt = 0; mt < 3; ++mt) {
                    acc[mt] = (v4f){0.f, 0.f, 0.f, 0.f};
                    acc[mt] = __builtin_amdgcn_mfma_f32_16x16x32_bf16(Af[mt][0], Bf[t][0], acc[mt], 0, 0, 0);
                    acc[mt] = __builtin_amdgcn_mfma_f32_16x16x32_bf16(Af[mt][1], Bf[t][1], acc[mt], 0, 0, 0);
                }
                if constexpr (V == 4) {
                    // MFMAONLY: keep every acc element live at zero inst cost
                    #pragma unroll
                    for (int mt = 0; mt < 3; ++mt)
                        asm volatile("" :: "v"(acc[mt][0]), "v"(acc[mt][1]),
                                            "v"(acc[mt][2]), "v"(acc[mt][3]));
                    best[t] = fmaxf(best[t], acc[0][0]);
                } else {
                    // softmax: 2^(x*log2e)=e^x, shift-free; pad chans via (s-3)
                    float s = 0.f, q = 0.f;
                    #pragma unroll
                    for (int mt = 0; mt < 3; ++mt) {
                        #pragma unroll
                        for (int r = 0; r < 4; ++r) {
                            const float e = (V == 2) ? acc[mt][r]
                                            : __builtin_amdgcn_exp2f(acc[mt][r]);
                            const float pv = __uint_as_float(
                                ((unsigned int)pu[t][mt][r]) << 16);
                            s += e;
                            q = fmaf(e, pv, q);
                        }
                    }
                    s += __shfl_xor(s, 16);  q += __shfl_xor(q, 16);
                    s += __shfl_xor(s, 32);  q += __shfl_xor(q, 32);
                    best[t] = fmaxf(best[t], q * __builtin_amdgcn_rcpf(s - 3.0f));
                }
            }
        }

        float* dst = (V == 0) ? outp : g_sink;
        if (g == 0) {
            #pragma unroll
            for (int t = 0; t < 4; ++t)
                dst[P0 + t * 16 + c] = best[t];
        }
    }
}

extern "C" void kernel_launch(void* const* d_in, const int* in_sizes, int n_in,
                              void* d_out, int out_size, void* d_ws, size_t ws_size,
                              hipStream_t stream) {
    const float* values  = (const float*)d_in[0];
    const float* rewards = (const float*)d_in[1];
    const float* weight  = (const float*)d_in[2];
    float* out = (float*)d_out;

    repack_kernel<<<96, 256, 0, stream>>>(weight);
    // FULL first (validated), then one-delta ablation variants (sink writes).
    vi_var<0><<<2048, 128, 0, stream>>>(values, rewards, out);   // FULL
    vi_var<1><<<2048, 128, 0, stream>>>(values, rewards, out);   // STAGE only
    vi_var<4><<<2048, 128, 0, stream>>>(values, rewards, out);   // + MFMA only
    vi_var<2><<<2048, 128, 0, stream>>>(values, rewards, out);   // FULL - exp2
}